// Round 5
// baseline (137.876 us; speedup 1.0000x reference)
//
#include <hip/hip_runtime.h>
#include <hip/hip_cooperative_groups.h>

namespace cg = cooperative_groups;

// ResiduePose fused single cooperative kernel.
// B=32, L=65536, f32. 1024 blocks x 256 threads, 2048 residues/block.
//   phase 1: block's trans -> LDS (24 KB) + partial sums -> d_ws
//   grid.sync()
//   phase 2: mean from 32 partials (L2-hit), 8 x 256-residue pose sub-chunks:
//            quat nontemporal loads (1 tile prefetch), trans from LDS,
//            output staged in LDS -> 3 coalesced nontemporal float4 stores.

#define BB 32
#define LL 65536
#define NBLK 1024
#define TPB 256
#define RPB 2048                          // residues per block
#define BLOCKS_PER_BATCH (NBLK / BB)      // 32

typedef float f32x4 __attribute__((ext_vector_type(4)));   // native vector: OK for nontemporal builtins

__global__ __launch_bounds__(TPB, 4) void fused_pose_kernel(
    const f32x4* __restrict__ trans4, const f32x4* __restrict__ quat4,
    float* __restrict__ partials, f32x4* __restrict__ out4) {

    __shared__ f32x4 strans[RPB * 3 / 4];   // 1536 float4 = 24 KB
    __shared__ f32x4 sout[TPB * 3];         // 768 float4 = 12 KB
    __shared__ float red[4][3];
    __shared__ float mean[3];

    const int tid = threadIdx.x;
    const int bid = blockIdx.x;

    // ---------------- phase 1: trans -> LDS + partial sums ----------------
    const size_t gbase = (size_t)bid * (RPB * 3 / 4);
    float s0 = 0.f, s1 = 0.f, s2 = 0.f;
#pragma unroll
    for (int it = 0; it < 2; ++it) {
        const int h = it * TPB + tid;        // residue-group (4 residues) in block
        const f32x4 a = __builtin_nontemporal_load(&trans4[gbase + (size_t)h * 3 + 0]);
        const f32x4 c = __builtin_nontemporal_load(&trans4[gbase + (size_t)h * 3 + 1]);
        const f32x4 d = __builtin_nontemporal_load(&trans4[gbase + (size_t)h * 3 + 2]);
        strans[h * 3 + 0] = a;
        strans[h * 3 + 1] = c;
        strans[h * 3 + 2] = d;
        s0 += a.x + a.w + c.z + d.y;
        s1 += a.y + c.x + c.w + d.z;
        s2 += a.z + c.y + d.x + d.w;
    }

    // prefetch first quat tile (in flight across the grid sync)
    const size_t qbase = (size_t)bid * RPB;
    f32x4 qcur = __builtin_nontemporal_load(&quat4[qbase + tid]);

#pragma unroll
    for (int off = 32; off > 0; off >>= 1) {
        s0 += __shfl_down(s0, off);
        s1 += __shfl_down(s1, off);
        s2 += __shfl_down(s2, off);
    }
    const int wave = tid >> 6;
    if ((tid & 63) == 0) { red[wave][0] = s0; red[wave][1] = s1; red[wave][2] = s2; }
    __syncthreads();
    if (tid == 0) {
        float a0 = 0.f, a1 = 0.f, a2 = 0.f;
#pragma unroll
        for (int w = 0; w < 4; ++w) { a0 += red[w][0]; a1 += red[w][1]; a2 += red[w][2]; }
        partials[bid * 3 + 0] = a0;
        partials[bid * 3 + 1] = a1;
        partials[bid * 3 + 2] = a2;
    }

    cg::this_grid().sync();

    // ---------------- phase 2: mean + pose ----------------
    const int b = bid / BLOCKS_PER_BATCH;
    if (tid < 3) {
        float s = 0.f;
#pragma unroll
        for (int p = 0; p < BLOCKS_PER_BATCH; ++p)
            s += partials[((size_t)b * BLOCKS_PER_BATCH + p) * 3 + tid];
        mean[tid] = s * (1.0f / (float)LL);
    }
    __syncthreads();
    const float mx = mean[0], my = mean[1], mz = mean[2];
    const float* sf = (const float*)strans;

    // idealized internal coords (N, CA=origin, C, CB)
    const float Nx = 1.460091f;
    const float Cx = -0.56431316f, Cy = 1.41695817f;
    const float Bx = -0.52426314f, By = -0.76611338f, Bz = 1.20561194f;

#pragma unroll 1
    for (int k = 0; k < RPB / TPB; ++k) {
        const f32x4 qnext = (k < RPB / TPB - 1)
            ? __builtin_nontemporal_load(&quat4[qbase + (k + 1) * TPB + tid])
            : qcur;

        const int r = k * TPB + tid;         // residue within block
        const float tx = sf[r * 3 + 0] - mx; // stride-3 LDS: 2-way, free
        const float ty = sf[r * 3 + 1] - my;
        const float tz = sf[r * 3 + 2] - mz;

        float rr = qcur.x, i = qcur.y, j = qcur.z, kk = qcur.w;
        const float inv = 1.0f / (sqrtf(rr * rr + i * i + j * j + kk * kk) + 1e-6f);
        rr *= inv; i *= inv; j *= inv; kk *= inv;

        const float R00 = 1.f - 2.f * (j * j + kk * kk);
        const float R01 = 2.f * (i * j - kk * rr);
        const float R02 = 2.f * (i * kk + j * rr);
        const float R10 = 2.f * (i * j + kk * rr);
        const float R11 = 1.f - 2.f * (i * i + kk * kk);
        const float R12 = 2.f * (j * kk - i * rr);
        const float R20 = 2.f * (i * kk - j * rr);
        const float R21 = 2.f * (j * kk + i * rr);
        const float R22 = 1.f - 2.f * (i * i + j * j);

        const float N0 = R00 * Nx + tx, N1 = R10 * Nx + ty, N2 = R20 * Nx + tz;
        const float C0 = R00 * Cx + R01 * Cy + tx;
        const float C1 = R10 * Cx + R11 * Cy + ty;
        const float C2 = R20 * Cx + R21 * Cy + tz;
        const float B0 = R00 * Bx + R01 * By + R02 * Bz + tx;
        const float B1 = R10 * Bx + R11 * By + R12 * Bz + ty;
        const float B2 = R20 * Bx + R21 * By + R22 * Bz + tz;

        __syncthreads();   // prior sub-chunk's stores have consumed sout
        sout[tid * 3 + 0] = (f32x4){N0, N1, N2, tx};
        sout[tid * 3 + 1] = (f32x4){ty, tz, C0, C1};
        sout[tid * 3 + 2] = (f32x4){C2, B0, B1, B2};
        __syncthreads();

        const size_t ob = ((size_t)bid * RPB + (size_t)k * TPB) * 3;
        __builtin_nontemporal_store(sout[0 * TPB + tid], &out4[ob + 0 * TPB + tid]);
        __builtin_nontemporal_store(sout[1 * TPB + tid], &out4[ob + 1 * TPB + tid]);
        __builtin_nontemporal_store(sout[2 * TPB + tid], &out4[ob + 2 * TPB + tid]);

        qcur = qnext;
    }
}

extern "C" void kernel_launch(void* const* d_in, const int* in_sizes, int n_in,
                              void* d_out, int out_size, void* d_ws, size_t ws_size,
                              hipStream_t stream) {
    const f32x4* trans4 = (const f32x4*)d_in[0];   // (B,L,3) f32
    const f32x4* quat4 = (const f32x4*)d_in[1];    // (B,L,4) f32
    f32x4* out4 = (f32x4*)d_out;                   // (B,L,4,3) f32
    float* partials = (float*)d_ws;                // NBLK*3 floats

    void* args[] = { (void*)&trans4, (void*)&quat4, (void*)&partials, (void*)&out4 };
    (void)hipLaunchCooperativeKernel((void*)fused_pose_kernel, dim3(NBLK), dim3(TPB),
                                     args, 0, stream);
}

// Round 6
// 33.832 us; speedup vs baseline: 4.0753x; 4.0753x over previous
//
#include <hip/hip_runtime.h>

// ResiduePose: coords[b,l,a,:] = R(q/|q|) · P[a] + (t[b,l] - mean_l t[b])
// B=32, L=65536, f32. Two-kernel structure (round 3, prediction-matched),
// tuned: PB=64 stage1 (1 residue-group/thread), coalesced mean gather in pose,
// nontemporal output stores.

#define BB 32
#define LL 65536
#define PB 64                             // partial-sum blocks per batch
#define RES_PER_BLOCK 256
#define POSE_BLOCKS ((BB * LL) / RES_PER_BLOCK)   // 8192

typedef float f32x4 __attribute__((ext_vector_type(4)));

// ---------------- stage 1: per-(batch, p) partial sums of translation ----------------
// 2048 blocks x 256 threads; each thread owns one residue-group (4 residues = 3 f32x4).
__global__ __launch_bounds__(256) void partial_sums_kernel(
    const f32x4* __restrict__ trans4, float* __restrict__ partials) {
    const int bid = blockIdx.x;                       // = b*PB + p
    // block tile: 256 residue-groups = 768 f32x4, thread h = tid
    const size_t base = (size_t)bid * 768;            // f32x4 index of tile start
    const size_t m = base + (size_t)threadIdx.x * 3;  // group start is phase-0 aligned

    const f32x4 a = trans4[m + 0];   // x0 y0 z0 x1
    const f32x4 c = trans4[m + 1];   // y1 z1 x2 y2
    const f32x4 d = trans4[m + 2];   // z2 x3 y3 z3
    float s0 = a.x + a.w + c.z + d.y;
    float s1 = a.y + c.x + c.w + d.z;
    float s2 = a.z + c.y + d.x + d.w;

#pragma unroll
    for (int off = 32; off > 0; off >>= 1) {
        s0 += __shfl_down(s0, off);
        s1 += __shfl_down(s1, off);
        s2 += __shfl_down(s2, off);
    }
    __shared__ float red[4][3];
    const int wave = threadIdx.x >> 6;
    if ((threadIdx.x & 63) == 0) {
        red[wave][0] = s0; red[wave][1] = s1; red[wave][2] = s2;
    }
    __syncthreads();
    if (threadIdx.x == 0) {
        float a0 = 0.f, a1 = 0.f, a2 = 0.f;
#pragma unroll
        for (int w = 0; w < 4; ++w) { a0 += red[w][0]; a1 += red[w][1]; a2 += red[w][2]; }
        float* dst = partials + (size_t)bid * 3;
        dst[0] = a0; dst[1] = a1; dst[2] = a2;
    }
}

// ---------------- stage 2: fused mean + pose, LDS-staged I/O, NT stores ----------------
__global__ __launch_bounds__(256) void pose_kernel(
    const f32x4* __restrict__ trans4, const f32x4* __restrict__ quat4,
    const float* __restrict__ partials, f32x4* __restrict__ out4) {
    __shared__ f32x4 stage[768];     // 12 KB: trans staging, then output staging
    __shared__ float sp[PB * 3];     // 192 partial floats for this batch
    __shared__ float mean[3];

    const int tid = threadIdx.x;
    const int b = blockIdx.x >> 8;                      // 256 pose-blocks per batch
    const size_t r0 = (size_t)blockIdx.x * RES_PER_BLOCK;

    // Phase A: coalesced trans staging (192 f32x4) + coalesced partial gather (192 floats)
    if (tid < 192) {
        stage[tid] = trans4[r0 * 3 / 4 + tid];
        sp[tid] = partials[(size_t)b * (PB * 3) + tid];   // L2-resident
    }
    __syncthreads();
    if (tid < 3) {
        float s = 0.f;
#pragma unroll
        for (int p = 0; p < PB; ++p) s += sp[p * 3 + tid];
        mean[tid] = s * (1.0f / (float)LL);
    }
    __syncthreads();

    const float mx = mean[0], my = mean[1], mz = mean[2];
    const float* sf = (const float*)stage;              // stride-3 scalar reads: free
    const float tx = sf[tid * 3 + 0] - mx;
    const float ty = sf[tid * 3 + 1] - my;
    const float tz = sf[tid * 3 + 2] - mz;

    const f32x4 q4 = quat4[r0 + tid];                   // perfect 16B/lane coalescing
    float r = q4.x, i = q4.y, j = q4.z, k = q4.w;
    const float inv = 1.0f / (sqrtf(r * r + i * i + j * j + k * k) + 1e-6f);
    r *= inv; i *= inv; j *= inv; k *= inv;

    const float R00 = 1.f - 2.f * (j * j + k * k);
    const float R01 = 2.f * (i * j - k * r);
    const float R02 = 2.f * (i * k + j * r);
    const float R10 = 2.f * (i * j + k * r);
    const float R11 = 1.f - 2.f * (i * i + k * k);
    const float R12 = 2.f * (j * k - i * r);
    const float R20 = 2.f * (i * k - j * r);
    const float R21 = 2.f * (j * k + i * r);
    const float R22 = 1.f - 2.f * (i * i + j * j);

    // idealized internal coords (N, CA=origin, C, CB)
    const float Nx = 1.460091f;
    const float Cx = -0.56431316f, Cy = 1.41695817f;
    const float Bx = -0.52426314f, By = -0.76611338f, Bz = 1.20561194f;

    const float N0 = R00 * Nx + tx, N1 = R10 * Nx + ty, N2 = R20 * Nx + tz;
    const float C0 = R00 * Cx + R01 * Cy + tx;
    const float C1 = R10 * Cx + R11 * Cy + ty;
    const float C2 = R20 * Cx + R21 * Cy + tz;
    const float B0 = R00 * Bx + R01 * By + R02 * Bz + tx;
    const float B1 = R10 * Bx + R11 * By + R12 * Bz + ty;
    const float B2 = R20 * Bx + R21 * By + R22 * Bz + tz;

    // Phase B: stage output in LDS
    __syncthreads();   // done reading trans staging
    stage[tid * 3 + 0] = (f32x4){N0, N1, N2, tx};
    stage[tid * 3 + 1] = (f32x4){ty, tz, C0, C1};
    stage[tid * 3 + 2] = (f32x4){C2, B0, B1, B2};
    __syncthreads();

    // Phase C: 3 lane-contiguous nontemporal f32x4 stores
    const size_t ob = r0 * 3;
    __builtin_nontemporal_store(stage[0 * 256 + tid], &out4[ob + 0 * 256 + tid]);
    __builtin_nontemporal_store(stage[1 * 256 + tid], &out4[ob + 1 * 256 + tid]);
    __builtin_nontemporal_store(stage[2 * 256 + tid], &out4[ob + 2 * 256 + tid]);
}

extern "C" void kernel_launch(void* const* d_in, const int* in_sizes, int n_in,
                              void* d_out, int out_size, void* d_ws, size_t ws_size,
                              hipStream_t stream) {
    const f32x4* trans4 = (const f32x4*)d_in[0];   // (B,L,3) f32
    const f32x4* quat4 = (const f32x4*)d_in[1];    // (B,L,4) f32
    f32x4* out4 = (f32x4*)d_out;                   // (B,L,4,3) f32
    float* partials = (float*)d_ws;                // BB*PB*3 = 6144 floats

    partial_sums_kernel<<<BB * PB, 256, 0, stream>>>(trans4, partials);
    pose_kernel<<<POSE_BLOCKS, 256, 0, stream>>>(trans4, quat4, partials, out4);
}